// Round 10
// baseline (661.638 us; speedup 1.0000x reference)
//
#include <hip/hip_runtime.h>
#include <stdint.h>

// Depthwise causal conv via MFMA Toeplitz, f16, 8-tile pipelined blocks.
//   y[p, q0+16t+j] = sum_r sum_k x[p+r-5, q0+16t-8+k] * B_r[k,j],
//   B_r[k,j] = w[r, k-j-3] for k-j-3 in [0,10], else 0.
// Each block owns one 64-col column x 8 consecutive 64-row tiles, with
// double-buffered LDS: issue loads(t+1) -> compute(t) -> convert+write(t+1)
// -> sync. Stage latency amortized; weights built once per block.
// N=2, C=16, H=W=2048.

#define HDIM 2048
#define WDIM 2048
#define CH   16
#define NT   8              // tiles per block (512 rows)
#define PITCH 88            // LDS row pitch in f16 (176B)
#define XROWS 69            // 64 + 5 halo rows
#define NSL   (XROWS * 20)  // float4 staging granules: 1380

typedef float    f32x4 __attribute__((ext_vector_type(4)));
typedef _Float16 f16x8 __attribute__((ext_vector_type(8)));
typedef _Float16 f16x4 __attribute__((ext_vector_type(4)));

__global__ __launch_bounds__(256, 6)
void dwconv_mfma(const float* __restrict__ x, const float* __restrict__ wgt,
                 float* __restrict__ out) {
  const int bx = blockIdx.x, plane = blockIdx.z;
  const int by0 = blockIdx.y * NT;   // first 64-row tile index
  const int q0 = bx * 64;
  const int tid = threadIdx.x;
  const size_t pb = (size_t)plane * HDIM * WDIM;
  const float* __restrict__ xp = x + pb;
  float* __restrict__ op = out + pb;

  // ---- All-zero block: entire 8-tile run strictly above diagonal ----
  if (bx >= by0 + NT) {
    const float4 z = make_float4(0.f, 0.f, 0.f, 0.f);
    for (int t = 0; t < NT; ++t) {
      const int p0 = (by0 + t) * 64;
#pragma unroll
      for (int i = 0; i < 4; ++i) {
        int idx = i * 256 + tid;
        int row = idx >> 4, c4 = idx & 15;
        *(float4*)(op + (size_t)(p0 + row) * WDIM + q0 + 4 * c4) = z;
      }
    }
    return;
  }

  __shared__ _Float16 sbuf[2][XROWS * PITCH];  // 2 x 12144 B -> 6 blocks/CU

  // tile class: 0 = strictly-upper(zero), 1 = pure(in-bounds+causal), 2 = masked
  auto tclass = [&](int p0) -> int {
    if (p0 + 63 < q0) return 0;
    return ((bx >= 1) && (bx <= 30) && (p0 >= q0 + 76)) ? 1 : 2;
  };

  // ---- Toeplitz B-fragments, once per block ----
  // B layout: lane holds B[k = 8*(lane>>4)+i, j = lane&15], i=0..7.
  const int lane = tid & 63;
  const int j16 = lane & 15;
  const int wk = lane >> 4;
  const int wid = tid >> 6;
  const float* __restrict__ wcp = wgt + (plane & (CH - 1)) * 66;
  f16x8 bw[6];
#pragma unroll
  for (int r = 0; r < 6; ++r) {
#pragma unroll
    for (int i = 0; i < 8; ++i) {
      int k = 8 * wk + i;
      int d = k - j16 - 3;  // tap index s
      bw[r][i] = (_Float16)((d >= 0 && d <= 10) ? wcp[r * 11 + d] : 0.f);
    }
  }

  // Full (synchronous) stage with bounds+causal predication; handles any tile.
  auto stageFull = [&](int p0, _Float16* buf) {
#pragma unroll
    for (int j = 0; j < 6; ++j) {
      int slot = j * 256 + tid;
      if (slot < NSL) {
        int row = slot / 20;
        int c4 = slot - row * 20;
        int ih = p0 - 5 + row;
        int cb = q0 - 8 + 4 * c4;
        float4 v = make_float4(0.f, 0.f, 0.f, 0.f);
        if (ih >= 0) {  // ih <= p0+63 <= 2047 always
          bool fullv = (cb >= 0) && (cb + 3 <= ih) && (cb + 3 < WDIM);
          if (fullv) {
            v = *(const float4*)(xp + (size_t)ih * WDIM + cb);
          } else {
            float* vv = &v.x;
#pragma unroll
            for (int e = 0; e < 4; ++e) {
              int iw = cb + e;
              if (iw >= 0 && iw < WDIM && iw <= ih)
                vv[e] = xp[(size_t)ih * WDIM + iw];
            }
          }
        }
        f16x4 h4;
        h4[0] = (_Float16)v.x; h4[1] = (_Float16)v.y;
        h4[2] = (_Float16)v.z; h4[3] = (_Float16)v.w;
        *(f16x4*)&buf[row * PITCH + 4 * c4] = h4;
      }
    }
  };

  // ---- Prologue: stage tile 0 ----
  {
    const int p00 = by0 * 64;
    if (tclass(p00) != 0) stageFull(p00, &sbuf[0][0]);
  }
  __syncthreads();

  // ---- Pipelined loop over 8 tiles ----
#pragma unroll 1
  for (int t = 0; t < NT; ++t) {
    const int p0t = (by0 + t) * 64;
    const int cls = tclass(p0t);
    const int p0n = p0t + 64;
    const int clsn = (t + 1 < NT) ? tclass(p0n) : -1;

    // (1) issue next tile's loads early (pure tiles only): latency hides
    //     under compute below (T14 issue-early / write-late).
    float4 pv[6];
    if (clsn == 1) {
#pragma unroll
      for (int j = 0; j < 6; ++j) {
        int slot = j * 256 + tid;
        if (slot < NSL) {
          int row = slot / 20;
          int c4 = slot - row * 20;
          pv[j] = *(const float4*)(xp + (size_t)(p0n - 5 + row) * WDIM +
                                   (q0 - 8 + 4 * c4));
        }
      }
    }

    // (2) compute tile t
    if (cls == 0) {
      const float4 z = make_float4(0.f, 0.f, 0.f, 0.f);
#pragma unroll
      for (int i = 0; i < 4; ++i) {
        int idx = i * 256 + tid;
        int row = idx >> 4, c4 = idx & 15;
        *(float4*)(op + (size_t)(p0t + row) * WDIM + q0 + 4 * c4) = z;
      }
    } else {
      const _Float16* __restrict__ lb = &sbuf[t & 1][0];
      f32x4 acc[4];
#pragma unroll
      for (int tt = 0; tt < 4; ++tt) acc[tt] = (f32x4){0.f, 0.f, 0.f, 0.f};
#pragma unroll
      for (int tt = 0; tt < 4; ++tt) {
#pragma unroll
        for (int r = 0; r < 6; ++r) {
          // A layout: lane holds A[m = lane&15, k = 8*(lane>>4)+i];
          // A[m,k] = x_tile[16*wid + m + r, 16*tt + k] (cols rel q0-8).
          int off = (16 * wid + j16 + r) * PITCH + 16 * tt + 8 * wk;
          f16x8 ah = *(const f16x8*)&lb[off];
          acc[tt] =
              __builtin_amdgcn_mfma_f32_16x16x32_f16(ah, bw[r], acc[tt], 0, 0, 0);
        }
      }
      // D layout: col = lane&15, row = 4*(lane>>4)+reg
      const bool needmask = (q0 + 63 > p0t);
#pragma unroll
      for (int tt = 0; tt < 4; ++tt) {
        const int q = q0 + 16 * tt + j16;
#pragma unroll
        for (int reg = 0; reg < 4; ++reg) {
          const int p = p0t + 16 * wid + 4 * wk + reg;
          float val = acc[tt][reg];
          if (needmask && q > p) val = 0.f;
          op[(size_t)p * WDIM + q] = val;
        }
      }
    }

    // (3) finish staging tile t+1 into the other buffer
    if (clsn == 1) {
#pragma unroll
      for (int j = 0; j < 6; ++j) {
        int slot = j * 256 + tid;
        if (slot < NSL) {
          int row = slot / 20;
          int c4 = slot - row * 20;
          f16x4 h4;
          h4[0] = (_Float16)pv[j].x; h4[1] = (_Float16)pv[j].y;
          h4[2] = (_Float16)pv[j].z; h4[3] = (_Float16)pv[j].w;
          *(f16x4*)&sbuf[(t + 1) & 1][row * PITCH + 4 * c4] = h4;
        }
      }
    } else if (clsn == 2) {
      stageFull(p0n, &sbuf[(t + 1) & 1][0]);
    }

    __syncthreads();
  }
}

extern "C" void kernel_launch(void* const* d_in, const int* in_sizes, int n_in,
                              void* d_out, int out_size, void* d_ws, size_t ws_size,
                              hipStream_t stream) {
  const float* x   = (const float*)d_in[0];
  const float* wgt = (const float*)d_in[1];
  float* out       = (float*)d_out;
  dim3 grid(WDIM / 64, HDIM / (64 * NT), 2 * CH);  // (32, 4, 32)
  dwconv_mfma<<<grid, dim3(256), 0, stream>>>(x, wgt, out);
}

// Round 11
// 384.918 us; speedup vs baseline: 1.7189x; 1.7189x over previous
//
#include <hip/hip_runtime.h>
#include <stdint.h>

// Depthwise causal conv via MFMA Toeplitz, f16, one-shot 128x128 blocks.
//   y[p,q] = sum_{r,s} w[r,s] * xm[p+r-5, q+s-5]   (xm causally masked)
// Operands swapped vs r8/r9: A = Toeplitz weights (m = local q), B = x tile
// (n = local p)  =>  lane's 4 acc regs = 4 consecutive q  =>  float4 stores.
//   A[m,k] = w[r, k-m-3] for k-m-3 in [0,10] else 0
//   B[k,n] = x[p0+16pt+n+r-5, q0+16qt-8+k]
// One-shot stage->sync->compute only: every pipelined variant (r3/r7/r10)
// spilled registers across the compute phase and exploded HBM traffic.
// N=2, C=16, H=W=2048.

#define HDIM 2048
#define WDIM 2048
#define CH   16

#define PITCH 144            // f16 per LDS row (288B) -> capacity-optimal b128
#define XROWS 133            // 128 + 5 halo rows
#define NGR   36             // 16B global granules (=8B LDS granules) per row
#define NSL   (XROWS * NGR)  // 4788
#define NJ    19             // ceil(NSL/256)

typedef float    f32x4 __attribute__((ext_vector_type(4)));
typedef _Float16 f16x8 __attribute__((ext_vector_type(8)));
typedef _Float16 f16x4 __attribute__((ext_vector_type(4)));

__global__ __launch_bounds__(256, 4)
void dwconv_mfma(const float* __restrict__ x, const float* __restrict__ wgt,
                 float* __restrict__ out) {
  const int bx = blockIdx.x, by = blockIdx.y, plane = blockIdx.z;
  const int q0 = bx * 128, p0 = by * 128;
  const int tid = threadIdx.x;
  const size_t pb = (size_t)plane * HDIM * WDIM;
  const float* __restrict__ xp = x + pb;
  float* __restrict__ op = out + pb;

  // ---- Strictly-upper block (by < bx): zeros only ----
  if (by < bx) {
    const float4 z = make_float4(0.f, 0.f, 0.f, 0.f);
#pragma unroll
    for (int i = 0; i < 16; ++i) {  // 128 rows x 32 float4
      int idx = i * 256 + tid;
      int row = idx >> 5, c4 = idx & 31;
      *(float4*)(op + (size_t)(p0 + row) * WDIM + q0 + 4 * c4) = z;
    }
    return;
  }

  __shared__ _Float16 sx[XROWS * PITCH];  // 38304 B -> 4 blocks/CU

  const int lane = tid & 63;
  const int j16 = lane & 15;   // A: m (local q) / B: n (local p) / D: col
  const int wk  = lane >> 4;   // k-octet index
  const int wid = tid >> 6;    // wave -> p-rows [32*wid, 32*wid+32)

  // ---- Toeplitz A-fragments (lane holds A[m=j16, k=8*wk+i]) ----
  const float* __restrict__ wcp = wgt + (plane & (CH - 1)) * 66;
  f16x8 aw[6];
#pragma unroll
  for (int r = 0; r < 6; ++r) {
#pragma unroll
    for (int i = 0; i < 8; ++i) {
      int d = 8 * wk + i - j16 - 3;  // tap index s
      aw[r][i] = (_Float16)((d >= 0 && d <= 10) ? wcp[r * 11 + d] : 0.f);
    }
  }

  // ---- Stage x tile as f16: rows [p0-5,p0+128), cols [q0-8,q0+136) ----
  // pure: all staged elems in-bounds AND causal (q0+135 <= p0-5  <=>  by>=bx+2)
  const bool pure = (bx >= 1) && (bx <= 14) && (by >= bx + 2);
#pragma unroll
  for (int j = 0; j < NJ; ++j) {
    int slot = j * 256 + tid;
    if (slot < NSL) {
      int row = slot / NGR;
      int c4 = slot - row * NGR;
      int ih = p0 - 5 + row;
      int cb = q0 - 8 + 4 * c4;
      float4 v = make_float4(0.f, 0.f, 0.f, 0.f);
      if (pure) {
        v = *(const float4*)(xp + (size_t)ih * WDIM + cb);
      } else if (ih >= 0) {  // ih <= p0+127 <= 2047 always
        bool fullv = (cb >= 0) && (cb + 3 <= ih) && (cb + 3 < WDIM);
        if (fullv) {
          v = *(const float4*)(xp + (size_t)ih * WDIM + cb);
        } else {
          float* vv = &v.x;
#pragma unroll
          for (int e = 0; e < 4; ++e) {
            int iw = cb + e;
            if (iw >= 0 && iw < WDIM && iw <= ih)
              vv[e] = xp[(size_t)ih * WDIM + iw];
          }
        }
      }
      f16x4 h4;
      h4[0] = (_Float16)v.x; h4[1] = (_Float16)v.y;
      h4[2] = (_Float16)v.z; h4[3] = (_Float16)v.w;
      *(f16x4*)&sx[row * PITCH + 4 * c4] = h4;
    }
  }

  __syncthreads();

  // ---- Compute: per wave 2 p-tiles x 8 q-tiles x 6 taps = 96 MFMA ----
  f32x4 acc[2][8];
#pragma unroll
  for (int pt = 0; pt < 2; ++pt)
#pragma unroll
    for (int qt = 0; qt < 8; ++qt) acc[pt][qt] = (f32x4){0.f, 0.f, 0.f, 0.f};

#pragma unroll
  for (int pt = 0; pt < 2; ++pt) {
#pragma unroll
    for (int qt = 0; qt < 8; ++qt) {
#pragma unroll
      for (int r = 0; r < 6; ++r) {
        // B[k=8wk+i, n=j16] = x_tile[16*(2wid+pt) + j16 + r, 16qt + 8wk + i]
        int off = (16 * (2 * wid + pt) + j16 + r) * PITCH + 16 * qt + 8 * wk;
        f16x8 xb = *(const f16x8*)&sx[off];
        acc[pt][qt] =
            __builtin_amdgcn_mfma_f32_16x16x32_f16(aw[r], xb, acc[pt][qt], 0, 0, 0);
      }
    }
  }

  // ---- Store: lane holds y[p0+32wid+16pt+j16, q0+16qt+4wk + (0..3)] ----
  const bool dmask = (by == bx);  // only exact-diagonal blocks cross p==q
#pragma unroll
  for (int pt = 0; pt < 2; ++pt) {
    const int p = p0 + 32 * wid + 16 * pt + j16;
#pragma unroll
    for (int qt = 0; qt < 8; ++qt) {
      const int q = q0 + 16 * qt + 4 * wk;
      f32x4 a = acc[pt][qt];
      if (dmask) {
#pragma unroll
        for (int reg = 0; reg < 4; ++reg)
          if (q + reg > p) a[reg] = 0.f;
      }
      *(float4*)(op + (size_t)p * WDIM + q) =
          make_float4(a[0], a[1], a[2], a[3]);
    }
  }
}

extern "C" void kernel_launch(void* const* d_in, const int* in_sizes, int n_in,
                              void* d_out, int out_size, void* d_ws, size_t ws_size,
                              hipStream_t stream) {
  const float* x   = (const float*)d_in[0];
  const float* wgt = (const float*)d_in[1];
  float* out       = (float*)d_out;
  dim3 grid(WDIM / 128, HDIM / 128, 2 * CH);  // (16, 16, 32)
  dwconv_mfma<<<grid, dim3(256), 0, stream>>>(x, wgt, out);
}